// Round 2
// baseline (1130.303 us; speedup 1.0000x reference)
//
#include <hip/hip_runtime.h>

// dictloss: ss_b = D@X + meanY; overlap-add over stride-1 patches; masked blend; A@v; MSE.
// Key identity: patches[p,k]=k+p  =>  ss_p_sum[n] = sum_a sum_p d[p,a]*x[a,n-p]  (FIR bank)
// plus meanY*npp[n] (npp given as input).
//
// R2 changes vs R1:
//  - atomic-free: conv writes NSPLIT partial buffers, vmask sums them;
//    gemv writes per-(m,chunk) partials, loss sums them. zero_kernel removed.
//  - staging: 5 global loads batched in-flight before LDS writes; predicate-free
//    fast path for interior rounds (only r==0 / tail / first+last n-chunk take slow path).
//  - NSPLIT 8->16: 1024 blocks, 3 blocks/CU resident (LDS 45.8 KB/block).

namespace {
constexpr int kP = 64;        // patch size
constexpr int kA = 256;       // atoms
constexpr int kN = 262144;    // signal length
constexpr int kK = 262081;    // npatches
constexpr int kM = 512;       // rows of A

// ---- conv kernel geometry ----
constexpr int CB = 256;             // threads per block
constexpr int OPT = 16;             // outputs per thread
constexpr int NB = CB * OPT;        // 4096 outputs per block
constexpr int NCHUNK = kN / NB;     // 64
constexpr int NSPLIT = 16;          // atom splits (partial buffers)
constexpr int APS = kA / NSPLIT;    // 16 atoms per block
constexpr int XS_LOG = NB + 64;     // 4160 logical staged floats (k in [n0-63, n0+NB])
constexpr int XS_L4 = XS_LOG / 4;   // 1040 logical float4
constexpr int XS_P4 = 1304;         // skewed physical float4 count (1299 needed + pad)
constexpr int R4 = XS_L4 + 1;       // 1041 staging float4 rounds
constexpr int GV_CH = 8;            // gemv column chunks per row

static_assert(APS == 16, "transpose loop assumes APS==16");

__device__ __forceinline__ float f4c(const float4& v, int i) {
  switch (i & 3) {
    case 0: return v.x;
    case 1: return v.y;
    case 2: return v.z;
    default: return v.w;
  }
}

// Stage x[a, n0-63 .. n0+NB] into LDS (zero-padded outside [0,kK)), with
// +4-float skew every 16 floats: phys(i) = i + 4*(i>>4).
// Alignment: (a*kK + n0 - 63) mod 4 == (a+1)&3 since kK%4==1, n0%4==0.
// Rounds r in [rlo, rhi) take the predicate-free fast path.
__device__ __forceinline__ void stage_row(const float* __restrict__ x,
                                          float* __restrict__ xsf,
                                          int a, int n0, int rlo, int rhi) {
  const int SA = (a + 1) & 3;
  const int gf = a * kK + n0 - 63 - SA;     // 16B-aligned float index (can be <0)
  const int g4base = gf >> 2;
  const float4* __restrict__ x4 = (const float4*)x;
  const int g4max = (kA * kK) / 4 - 1;
  float4 vals[5];
#pragma unroll
  for (int u = 0; u < 5; ++u) {             // all loads issued before any LDS write
    int r = (int)threadIdx.x + u * CB;
    if (r < R4) {
      int g4 = g4base + r;
      g4 = g4 < 0 ? 0 : (g4 > g4max ? g4max : g4);  // mem-safe; OOB zeroed in slow path
      vals[u] = x4[g4];
    }
  }
#pragma unroll
  for (int u = 0; u < 5; ++u) {
    int r = (int)threadIdx.x + u * CB;
    if (r >= R4) continue;
    if (r >= rlo && r < rhi) {              // fast path: no per-element predicates
      const int i0 = 4 * r - SA;
#pragma unroll
      for (int w = 0; w < 4; ++w) {
        int i = i0 + w;
        xsf[i + 4 * (i >> 4)] = f4c(vals[u], w);
      }
    } else {                                // edge rounds: full checks
#pragma unroll
      for (int w = 0; w < 4; ++w) {
        int i = 4 * r + w - SA;
        if ((unsigned)i < (unsigned)XS_LOG) {
          int k = n0 - 63 + i;
          float f = ((unsigned)k < (unsigned)kK) ? f4c(vals[u], w) : 0.0f;
          xsf[i + 4 * (i >> 4)] = f;
        }
      }
    }
  }
}

// acc[j] (j=0..15) += sum_q d[63-q] * xs[tid*16 + j + q], q = 0..63.
// Rolling 5-float4 register window; all indices compile-time after full unroll.
__device__ __forceinline__ void compute_atom(const float4* __restrict__ xs4,
                                             const float4* __restrict__ dt4,
                                             int a_loc, float* __restrict__ acc) {
  const int t4 = threadIdx.x * 4;
  float4 w[5];
#pragma unroll
  for (int q = 0; q < 4; ++q) {
    int l4 = t4 + q;
    w[q] = xs4[l4 + (l4 >> 2)];                    // phys4 = l4 + l4/4 (exact: t4%4==0)
  }
#pragma unroll
  for (int c = 0; c < 16; ++c) {
    {
      int l4 = t4 + c + 4;
      w[(c + 4) % 5] = xs4[l4 + (l4 >> 2)];
    }
    float4 D = dt4[a_loc * 16 + 15 - c];           // dT[p=60-4c .. 63-4c]
    float dc[4] = {D.w, D.z, D.y, D.x};            // dc[i] = d[63-4c-i] = coef for q=4c+i
#pragma unroll
    for (int i = 0; i < 4; ++i) {
      float coef = dc[i];
#pragma unroll
      for (int j = 0; j < OPT; ++j) {
        int off = i + j;                           // 0..18
        float xv = f4c(w[(c + (off >> 2)) % 5], off & 3);
        acc[j] = fmaf(coef, xv, acc[j]);
      }
    }
  }
}

__global__ __launch_bounds__(CB, 3) void conv_kernel(const float* __restrict__ d,
                                                     const float* __restrict__ x,
                                                     float* __restrict__ part) {
  __shared__ float4 xsA[XS_P4];
  __shared__ float4 xsB[XS_P4];
  __shared__ float4 dt4[APS * 16];                 // dT[a_loc][p], row stride 64 floats
  const int n0 = blockIdx.x * NB;
  const int a0 = blockIdx.y * APS;
  const int tid = threadIdx.x;
  const int rlo = (blockIdx.x == 0) ? 17 : 1;          // first chunk: k<0 until r=16
  const int rhi = (blockIdx.x == NCHUNK - 1) ? 1024 : 1040;  // last chunk: k>=kK from r=1024

  // one-time: transpose this block's d columns into LDS
  float* dtf = (float*)dt4;
#pragma unroll 1
  for (int i = tid; i < APS * kP; i += CB) {
    int al = i & (APS - 1);
    int p = i >> 4;                                // APS == 16
    dtf[al * kP + p] = d[p * kA + a0 + al];
  }

  float acc[OPT];
#pragma unroll
  for (int j = 0; j < OPT; ++j) acc[j] = 0.0f;

  stage_row(x, (float*)xsA, a0, n0, rlo, rhi);
  __syncthreads();

#pragma unroll 1
  for (int a = 0; a < APS; a += 2) {               // double-buffered: 1 barrier per atom
    stage_row(x, (float*)xsB, a0 + a + 1, n0, rlo, rhi);
    compute_atom(xsA, dt4, a, acc);
    __syncthreads();
    if (a + 2 < APS) stage_row(x, (float*)xsA, a0 + a + 2, n0, rlo, rhi);
    compute_atom(xsB, dt4, a + 1, acc);
    __syncthreads();
  }

  // atomic-free: each split writes its own kN-sized partial buffer
  float4* outp = (float4*)(part + (size_t)blockIdx.y * kN + n0 + tid * OPT);
#pragma unroll
  for (int j = 0; j < 4; ++j)
    outp[j] = make_float4(acc[4 * j], acc[4 * j + 1], acc[4 * j + 2], acc[4 * j + 3]);
}

__global__ void vmask_kernel(const float* __restrict__ part, const float* __restrict__ ds,
                             const float* __restrict__ npp, const float* __restrict__ vb,
                             const float* __restrict__ sRef,
                             const float* __restrict__ pMeanY,
                             const float* __restrict__ pLam2, float* __restrict__ v) {
  const int i = blockIdx.x * blockDim.x + threadIdx.x;   // float4 index over kN/4
  const float meanY = pMeanY[0];
  const float lam2 = pLam2[0];
  float4 s = make_float4(0.f, 0.f, 0.f, 0.f);
#pragma unroll
  for (int c = 0; c < NSPLIT; ++c) {
    float4 p = ((const float4*)(part + (size_t)c * kN))[i];
    s.x += p.x; s.y += p.y; s.z += p.z; s.w += p.w;
  }
  const float4 dd = ((const float4*)ds)[i];
  const float4 np = ((const float4*)npp)[i];
  const float4 vbv = ((const float4*)vb)[i];
  const float4 sr = ((const float4*)sRef)[i];
  float4 r;
  r.x = (lam2 * dd.x + s.x + meanY * np.x) / (lam2 + np.x) * vbv.x + sr.x;
  r.y = (lam2 * dd.y + s.y + meanY * np.y) / (lam2 + np.y) * vbv.y + sr.y;
  r.z = (lam2 * dd.z + s.z + meanY * np.z) / (lam2 + np.z) * vbv.z + sr.z;
  r.w = (lam2 * dd.w + s.w + meanY * np.w) / (lam2 + np.w) * vbv.w + sr.w;
  ((float4*)v)[i] = r;
}

__global__ __launch_bounds__(256) void gemv_kernel(const float* __restrict__ A,
                                                   const float* __restrict__ v,
                                                   float* __restrict__ Tp) {
  const int m = blockIdx.x >> 3;                   // GV_CH == 8
  const int ch = blockIdx.x & (GV_CH - 1);
  const float4* __restrict__ A4 = (const float4*)(A + (size_t)m * kN);
  const float4* __restrict__ v4 = (const float4*)v;
  const int b0 = ch * (kN / 4 / GV_CH) + threadIdx.x;
  float s = 0.0f;
#pragma unroll 8
  for (int r = 0; r < 32; ++r) {
    float4 av = A4[b0 + r * 256];
    float4 vv = v4[b0 + r * 256];
    s = fmaf(av.x, vv.x, s);
    s = fmaf(av.y, vv.y, s);
    s = fmaf(av.z, vv.z, s);
    s = fmaf(av.w, vv.w, s);
  }
#pragma unroll
  for (int o = 32; o > 0; o >>= 1) s += __shfl_down(s, o, 64);
  __shared__ float red[4];
  if ((threadIdx.x & 63) == 0) red[threadIdx.x >> 6] = s;
  __syncthreads();
  if (threadIdx.x == 0) Tp[blockIdx.x] = red[0] + red[1] + red[2] + red[3];
}

__global__ void loss_kernel(const float* __restrict__ Tp, const float* __restrict__ Tarr,
                            float* __restrict__ out) {
  const int tid = threadIdx.x;
  float s = 0.0f;
  for (int m = tid; m < kM; m += 256) {
    float t = 0.0f;
#pragma unroll
    for (int c = 0; c < GV_CH; ++c) t += Tp[m * GV_CH + c];
    float df = t - Tarr[m];
    s = fmaf(df, df, s);
  }
#pragma unroll
  for (int o = 32; o > 0; o >>= 1) s += __shfl_down(s, o, 64);
  __shared__ float red[4];
  if ((tid & 63) == 0) red[tid >> 6] = s;
  __syncthreads();
  if (tid == 0) out[0] = (red[0] + red[1] + red[2] + red[3]) * (1.0f / kM);
}

}  // namespace

extern "C" void kernel_launch(void* const* d_in, const int* in_sizes, int n_in,
                              void* d_out, int out_size, void* d_ws, size_t ws_size,
                              hipStream_t stream) {
  const float* d    = (const float*)d_in[0];   // [1,64,256]
  const float* x    = (const float*)d_in[1];   // [256, 262081]
  const float* vb   = (const float*)d_in[3];   // [N,1]
  const float* npp  = (const float*)d_in[5];   // [N,1]
  const float* sRef = (const float*)d_in[6];   // [N,1]
  const float* A    = (const float*)d_in[7];   // [512, N]
  const float* Tarr = (const float*)d_in[8];   // [512,1]
  const float* pMeanY = (const float*)d_in[9];
  const float* ds   = (const float*)d_in[10];
  const float* pLam2 = (const float*)d_in[11];
  float* out = (float*)d_out;

  // workspace layout (floats): part[NSPLIT*kN] | v[kN] | Tp[kM*GV_CH]  (~17.1 MB)
  float* part = (float*)d_ws;
  float* v    = part + (size_t)NSPLIT * kN;
  float* Tp   = v + kN;

  conv_kernel<<<dim3(NCHUNK, NSPLIT), CB, 0, stream>>>(d, x, part);
  vmask_kernel<<<kN / 4 / 256, 256, 0, stream>>>(part, ds, npp, vb, sRef, pMeanY, pLam2, v);
  gemv_kernel<<<kM * GV_CH, 256, 0, stream>>>(A, v, Tp);
  loss_kernel<<<1, 256, 0, stream>>>(Tp, Tarr, out);
}

// Round 3
// 913.824 us; speedup vs baseline: 1.2369x; 1.2369x over previous
//
#include <hip/hip_runtime.h>

// dictloss: ss_b = D@X + meanY; overlap-add over stride-1 patches; masked blend; A@v; MSE.
// Key identity: patches[p,k]=k+p  =>  ss_p_sum[n] = sum_a sum_p d[p,a]*x[a,n-p]  (FIR bank)
// plus meanY*npp[n] (npp given as input).
//
// R3 changes vs R2 (conv was 350us, stall-bound: VALUBusy 21%, 1.1e7 LDS write conflicts,
// in-wave vmcnt serialization):
//  - staging via __builtin_amdgcn_global_load_lds width=16: async HW global->LDS, no VGPR
//    round-trip, no LDS write conflicts, loads overlap compute (m97 structure).
//  - per-atom misalignment SA=(a+1)&3 folded into a zero-padded pre-reversed 68-tap
//    coefficient table in LDS -> single SA-independent compute_atom (I$-friendly).
//  - XOR swizzle l4 ^ ((l4>>3)&7) (self-inverse) applied to per-lane global address at
//    stage time and LDS read index at compute: reads are 2-way/phase = conflict-free.
//  - 4 blocks/CU (39.9 KB LDS), 16 waves/CU.

namespace {
constexpr int kP = 64;        // patch size
constexpr int kA = 256;       // atoms
constexpr int kN = 262144;    // signal length
constexpr int kK = 262081;    // npatches
constexpr int kM = 512;       // rows of A

constexpr int CB = 256;             // threads per conv block
constexpr int OPT = 16;             // outputs per thread
constexpr int NB = CB * OPT;        // 4096 outputs per block
constexpr int NCHUNK = kN / NB;     // 64
constexpr int NSPLIT = 16;          // atom splits (partial buffers)
constexpr int APS = kA / NSPLIT;    // 16 atoms per block
constexpr int XS4 = 1088;           // float4 slots per x buffer (1044 staged + pad)
constexpr int DPF = 80;             // floats per padded/reversed coefficient row
constexpr int GV_CH = 8;            // gemv column chunks per row

__device__ __forceinline__ int swz(int l4) { return l4 ^ ((l4 >> 3) & 7); }

__device__ __forceinline__ float f4c(const float4& v, int i) {
  switch (i & 3) {
    case 0: return v.x;
    case 1: return v.y;
    case 2: return v.z;
    default: return v.w;
  }
}

__device__ __forceinline__ void gload_lds16(const void* g, void* l) {
  __builtin_amdgcn_global_load_lds(
      (const __attribute__((address_space(1))) unsigned int*)g,
      (__attribute__((address_space(3))) unsigned int*)l, 16, 0, 0);
}

// Async-stage x[a, k0 .. k0+4175], k0 = n0-63-SA (16B-aligned since kK%4==1), into buf.
// LDS slot p holds global float4 (g4base + swz(p & 63) + (p & ~63)); swz is self-inverse,
// so compute reads xs4[swz(l4)] to get logical float4 l4. OOB addresses clamped (edge
// blocks overwrite those slots with zeros before compute).
__device__ __forceinline__ void stage(const float* __restrict__ x, float4* buf,
                                      int a, int n0, int tid) {
  const int SA = (a + 1) & 3;
  const int g4base = (a * kK + n0 - 63 - SA) >> 2;
  const int g4max = (kA / 4) * kK - 1;
  const float4* __restrict__ x4 = (const float4*)x;
  const int wav = tid >> 6, lane = tid & 63;
  const int sl = lane ^ ((lane >> 3) & 7);
#pragma unroll
  for (int r = 0; r < 4; ++r) {
    const int s = r * 4 + wav;                     // 16 segments of 64 float4
    int g4 = g4base + s * 64 + sl;
    g4 = g4 < 0 ? 0 : (g4 > g4max ? g4max : g4);
    gload_lds16(x4 + g4, buf + s * 64);            // wave-uniform LDS base + lane*16B
  }
  if (tid < 20) {                                  // tail: slots 1024..1043 (wave 0)
    int g4 = g4base + 1024 + (tid ^ ((tid >> 3) & 7));
    g4 = g4 < 0 ? 0 : (g4 > g4max ? g4max : g4);
    gload_lds16(x4 + g4, buf + 1024);
  }
}

// acc[j] += sum_{q'=0..67} dp[q'] * xs[16t + j + q'], dp pre-reversed & zero-padded.
__device__ __forceinline__ void compute_atom(const float4* __restrict__ xs4,
                                             const float* __restrict__ dpf,
                                             int al, float* __restrict__ acc) {
  const int t4 = (int)threadIdx.x * 4;
  const float4* __restrict__ dp4 = (const float4*)(dpf + al * DPF);
  float4 w[5];
#pragma unroll
  for (int q = 0; q < 4; ++q) w[q] = xs4[swz(t4 + q)];
#pragma unroll
  for (int c = 0; c < 17; ++c) {
    w[(c + 4) % 5] = xs4[swz(t4 + c + 4)];
    float4 D = dp4[c];
#pragma unroll
    for (int i = 0; i < 4; ++i) {
      float coef = f4c(D, i);
#pragma unroll
      for (int j = 0; j < OPT; ++j) {
        int off = i + j;                           // 0..18
        acc[j] = fmaf(coef, f4c(w[(c + (off >> 2)) % 5], off & 3), acc[j]);
      }
    }
  }
}

__global__ __launch_bounds__(CB, 4) void conv_kernel(const float* __restrict__ d,
                                                     const float* __restrict__ x,
                                                     float* __restrict__ part) {
  __shared__ float4 xsA[XS4];
  __shared__ float4 xsB[XS4];
  __shared__ float dpf[APS * DPF];
  const int n0 = blockIdx.x * NB;
  const int a0 = blockIdx.y * APS;
  const int tid = threadIdx.x;

  // Build padded+reversed coefficient table: dp[al][q'] = d[63+SA-q'][a0+al] for
  // q' in [SA, SA+63], else 0.  out[n] = sum_q' dp[q']*x[k0+16t+j+q'].
  for (int idx = tid; idx < APS * DPF; idx += CB) {
    int al = idx / DPF, q = idx - al * DPF;
    int a = a0 + al, SA = (a + 1) & 3;
    float v = 0.0f;
    if (q >= SA && q < SA + 64) v = d[(63 + SA - q) * kA + a];
    dpf[idx] = v;
  }

  stage(x, xsA, a0, n0, tid);
  __syncthreads();                                 // dpf + bufA ready (drains vmcnt)

  float acc[OPT];
#pragma unroll
  for (int j = 0; j < OPT; ++j) acc[j] = 0.0f;

  const bool first = (blockIdx.x == 0);
  const bool last = (blockIdx.x == NCHUNK - 1);

#pragma unroll 1
  for (int al = 0; al < APS; ++al) {
    float4* cur = (al & 1) ? xsB : xsA;
    float4* nxt = (al & 1) ? xsA : xsB;
    const int a = a0 + al;
    if (first | last) {                            // block-uniform; 2/64 of n-chunks
      const int SA = (a + 1) & 3;
      float* curf = (float*)cur;
      if (first) {
        if (tid < 63 + SA) {                       // zero k<0 halo (floats 0..62+SA)
          int slot = swz(tid >> 2);
          curf[slot * 4 + (tid & 3)] = 0.0f;
        }
      } else {
        const int iK = kK - n0 + 63 + SA;          // zero k>=kK tail
        for (int i = iK + tid; i < 4176; i += CB) {
          int slot = swz(i >> 2);
          curf[slot * 4 + (i & 3)] = 0.0f;
        }
      }
      __syncthreads();
    }
    if (al + 1 < APS) stage(x, nxt, a0 + al + 1, n0, tid);   // async prefetch
    compute_atom(cur, dpf, al, acc);
    __syncthreads();                               // nxt landed; cur free to restage
  }

  float4* outp = (float4*)(part + (size_t)blockIdx.y * kN + n0 + tid * OPT);
#pragma unroll
  for (int j = 0; j < 4; ++j)
    outp[j] = make_float4(acc[4 * j], acc[4 * j + 1], acc[4 * j + 2], acc[4 * j + 3]);
}

__global__ void vmask_kernel(const float* __restrict__ part, const float* __restrict__ ds,
                             const float* __restrict__ npp, const float* __restrict__ vb,
                             const float* __restrict__ sRef,
                             const float* __restrict__ pMeanY,
                             const float* __restrict__ pLam2, float* __restrict__ v) {
  const int i = blockIdx.x * blockDim.x + threadIdx.x;   // float4 index over kN/4
  const float meanY = pMeanY[0];
  const float lam2 = pLam2[0];
  float4 s = make_float4(0.f, 0.f, 0.f, 0.f);
#pragma unroll
  for (int c = 0; c < NSPLIT; ++c) {
    float4 p = ((const float4*)(part + (size_t)c * kN))[i];
    s.x += p.x; s.y += p.y; s.z += p.z; s.w += p.w;
  }
  const float4 dd = ((const float4*)ds)[i];
  const float4 np = ((const float4*)npp)[i];
  const float4 vbv = ((const float4*)vb)[i];
  const float4 sr = ((const float4*)sRef)[i];
  float4 r;
  r.x = (lam2 * dd.x + s.x + meanY * np.x) / (lam2 + np.x) * vbv.x + sr.x;
  r.y = (lam2 * dd.y + s.y + meanY * np.y) / (lam2 + np.y) * vbv.y + sr.y;
  r.z = (lam2 * dd.z + s.z + meanY * np.z) / (lam2 + np.z) * vbv.z + sr.z;
  r.w = (lam2 * dd.w + s.w + meanY * np.w) / (lam2 + np.w) * vbv.w + sr.w;
  ((float4*)v)[i] = r;
}

__global__ __launch_bounds__(256) void gemv_kernel(const float* __restrict__ A,
                                                   const float* __restrict__ v,
                                                   float* __restrict__ Tp) {
  const int m = blockIdx.x >> 3;                   // GV_CH == 8
  const int ch = blockIdx.x & (GV_CH - 1);
  const float4* __restrict__ A4 = (const float4*)(A + (size_t)m * kN);
  const float4* __restrict__ v4 = (const float4*)v;
  const int b0 = ch * (kN / 4 / GV_CH) + threadIdx.x;
  float s = 0.0f;
#pragma unroll 8
  for (int r = 0; r < 32; ++r) {
    float4 av = A4[b0 + r * 256];
    float4 vv = v4[b0 + r * 256];
    s = fmaf(av.x, vv.x, s);
    s = fmaf(av.y, vv.y, s);
    s = fmaf(av.z, vv.z, s);
    s = fmaf(av.w, vv.w, s);
  }
#pragma unroll
  for (int o = 32; o > 0; o >>= 1) s += __shfl_down(s, o, 64);
  __shared__ float red[4];
  if ((threadIdx.x & 63) == 0) red[threadIdx.x >> 6] = s;
  __syncthreads();
  if (threadIdx.x == 0) Tp[blockIdx.x] = red[0] + red[1] + red[2] + red[3];
}

__global__ void loss_kernel(const float* __restrict__ Tp, const float* __restrict__ Tarr,
                            float* __restrict__ out) {
  const int tid = threadIdx.x;
  float s = 0.0f;
  for (int m = tid; m < kM; m += 256) {
    float t = 0.0f;
#pragma unroll
    for (int c = 0; c < GV_CH; ++c) t += Tp[m * GV_CH + c];
    float df = t - Tarr[m];
    s = fmaf(df, df, s);
  }
#pragma unroll
  for (int o = 32; o > 0; o >>= 1) s += __shfl_down(s, o, 64);
  __shared__ float red[4];
  if ((tid & 63) == 0) red[tid >> 6] = s;
  __syncthreads();
  if (tid == 0) out[0] = (red[0] + red[1] + red[2] + red[3]) * (1.0f / kM);
}

}  // namespace

extern "C" void kernel_launch(void* const* d_in, const int* in_sizes, int n_in,
                              void* d_out, int out_size, void* d_ws, size_t ws_size,
                              hipStream_t stream) {
  const float* d    = (const float*)d_in[0];   // [1,64,256]
  const float* x    = (const float*)d_in[1];   // [256, 262081]
  const float* vb   = (const float*)d_in[3];   // [N,1]
  const float* npp  = (const float*)d_in[5];   // [N,1]
  const float* sRef = (const float*)d_in[6];   // [N,1]
  const float* A    = (const float*)d_in[7];   // [512, N]
  const float* Tarr = (const float*)d_in[8];   // [512,1]
  const float* pMeanY = (const float*)d_in[9];
  const float* ds   = (const float*)d_in[10];
  const float* pLam2 = (const float*)d_in[11];
  float* out = (float*)d_out;

  // workspace layout (floats): part[NSPLIT*kN] | v[kN] | Tp[kM*GV_CH]  (~17.1 MB)
  float* part = (float*)d_ws;
  float* v    = part + (size_t)NSPLIT * kN;
  float* Tp   = v + kN;

  conv_kernel<<<dim3(NCHUNK, NSPLIT), CB, 0, stream>>>(d, x, part);
  vmask_kernel<<<kN / 4 / 256, 256, 0, stream>>>(part, ds, npp, vb, sRef, pMeanY, pLam2, v);
  gemv_kernel<<<kM * GV_CH, 256, 0, stream>>>(A, v, Tp);
  loss_kernel<<<1, 256, 0, stream>>>(Tp, Tarr, out);
}